// Round 4
// baseline (354.020 us; speedup 1.0000x reference)
//
#include <hip/hip_runtime.h>
#include <stdint.h>

// B=4 N=32 L=S=256 H=8 E=D=64
// grid = B*N*H = 1024 blocks, 1024 threads (16 waves), one (b,n,h) per block.
// Each wave owns 16 q-rows. Swapped-operand MFMA: QK tile D[s][q] (col=q=lane&15),
// PV tile D[d][q]. LDS 70.9KB -> 2 blocks/CU; VGPR capped 64 -> 32 waves/CU.
// R4: depth-2 software pipeline on the prior (attn_scores) stream.

typedef __attribute__((ext_vector_type(8))) short bfrag;   // 8 bf16 (4 VGPRs)
typedef __attribute__((ext_vector_type(4))) float f32x4;
typedef __attribute__((ext_vector_type(4))) int i32x4;

__device__ __forceinline__ uint32_t f2bf(float f) {
  uint32_t u = __builtin_bit_cast(uint32_t, f);
  return (u + 0x7FFFu + ((u >> 16) & 1u)) >> 16;   // RNE f32->bf16 (finite data)
}
__device__ __forceinline__ uint32_t pk(float a, float b) {
  return f2bf(a) | (f2bf(b) << 16);
}

#define MFMA(a, b, c) __builtin_amdgcn_mfma_f32_16x16x32_bf16((a), (b), (c), 0, 0, 0)

__global__ __launch_bounds__(1024, 8) void attn_kernel(
    const float* __restrict__ Qg, const float* __restrict__ Kg,
    const float* __restrict__ Vg, const float* __restrict__ Pg,
    float* __restrict__ Sc, float* __restrict__ Ov)
{
  // K rows padded to 72 shorts (2-way bank alias = free); Vt rows 266 shorts.
  __shared__ unsigned short Ks[256 * 72];   // 36864 B
  __shared__ unsigned short Vt[64 * 266];   // 34048 B  (total 70912 B)

  const int bnh = blockIdx.x;
  const int bn = bnh >> 3, h = bnh & 7;
  const int t = threadIdx.x;

  // ---- stage K as bf16 [s][e] : 64 rows/iter x 4 iters ----
  {
    const int e0 = (t & 15) * 4;
    const int rb = t >> 4;                       // 0..63
    const float* kp = Kg + (size_t)bn * 131072 + h * 64 + e0;
#pragma unroll
    for (int it = 0; it < 4; ++it) {
      const int r = it * 64 + rb;
      const f32x4 k4 = *(const f32x4*)(kp + (size_t)r * 512);
      uint2 kk;
      kk.x = pk(k4.x, k4.y);
      kk.y = pk(k4.z, k4.w);
      *(uint2*)(&Ks[r * 72 + e0]) = kk;
    }
  }
  // ---- stage V transposed as bf16 [d][s] : 16 s-groups x 4 iters ----
  {
    const int d = t & 63, sg = t >> 6;           // sg 0..15
    const float* vp = Vg + (size_t)bn * 131072 + h * 64 + d;
#pragma unroll
    for (int it = 0; it < 4; ++it) {
      const int sv = it * 64 + sg * 4;
      const float v0 = vp[(size_t)(sv + 0) * 512];
      const float v1 = vp[(size_t)(sv + 1) * 512];
      const float v2 = vp[(size_t)(sv + 2) * 512];
      const float v3 = vp[(size_t)(sv + 3) * 512];
      uint2 vv;
      vv.x = pk(v0, v1);
      vv.y = pk(v2, v3);
      *(uint2*)(&Vt[d * 266 + sv]) = vv;
    }
  }

  const int lane = t & 63;
  const int wave = t >> 6;    // 0..15
  const int ql = lane & 15;   // q within 16-tile (MFMA col)
  const int g  = lane >> 4;   // 4-group (MFMA row group / k-slice)
  const int qbase = wave * 16;
  const int q = qbase + ql;
  const float temp = 0.125f;  // 1/sqrt(64)

  // ---- Q fragments direct from global (B-operand of swapped QK) ----
  bfrag qf[2];
#pragma unroll
  for (int ks = 0; ks < 2; ++ks) {
    const float* qp = Qg + (size_t)bn * 131072 + (size_t)q * 512 + h * 64 + ks * 32 + g * 8;
    const f32x4 qa = *(const f32x4*)qp;
    const f32x4 qb = *(const f32x4*)(qp + 4);
    union { i32x4 i; bfrag b; } u;
    u.i = i32x4{(int)pk(qa.x, qa.y), (int)pk(qa.z, qa.w),
                (int)pk(qb.x, qb.y), (int)pk(qb.z, qb.w)};
    qf[ks] = u.b;
  }

  __syncthreads();

  f32x4 O[4];
#pragma unroll
  for (int ds = 0; ds < 4; ++ds) O[ds] = f32x4{0.f, 0.f, 0.f, 0.f};
  float m = -1e30f, lsum = 0.f;

  const size_t scb = (size_t)bnh << 16;
  const float* prp = Pg + scb + (size_t)q * 256 + 4 * g;   // + 16*ss + 32*st
  float* scp = Sc + scb + (size_t)q * 256 + 4 * g;
  const int pvmax = wave >> 1;   // causal: PV only for st <= pvmax

  // depth-2 prior pipeline: prA holds tile st (even), prB tile st+1 (odd)
  f32x4 prA[2], prB[2];
#pragma unroll
  for (int ss = 0; ss < 2; ++ss) {
    prA[ss] = __builtin_nontemporal_load((const f32x4*)(prp + 16 * ss));
    prB[ss] = __builtin_nontemporal_load((const f32x4*)(prp + 32 + 16 * ss));
  }

  auto tile_body = [&](int st, f32x4* pr) {
    const int s0 = st * 32;
    bfrag kf[2][2];
#pragma unroll
    for (int ss = 0; ss < 2; ++ss)
#pragma unroll
      for (int ks = 0; ks < 2; ++ks)
        kf[ss][ks] = *(const bfrag*)(&Ks[(s0 + 16 * ss + ql) * 72 + ks * 32 + g * 8]);

    // QK^T swapped -> D[s16][q16]; regs are s-consecutive at fixed q
    f32x4 acc[2];
#pragma unroll
    for (int ss = 0; ss < 2; ++ss) {
      f32x4 a = f32x4{0.f, 0.f, 0.f, 0.f};
      a = MFMA(kf[ss][0], qf[0], a);
      a = MFMA(kf[ss][1], qf[1], a);
      const int sb = s0 + 16 * ss + 4 * g;
      // analytic causal mask: s<=q allowed, else -1e9 (matches input mask)
#pragma unroll
      for (int r = 0; r < 4; ++r)
        a[r] = (sb + r <= q) ? a[r] : a[r] - 1e9f;
      acc[ss] = a + pr[ss];   // scores = QK + mask + prior
    }
    // prefetch prior for tile st+2 into the buffer just consumed
    // (clamped: last two issues re-load tile 7, dead but branch-free)
    const int tf = (st + 2 < 8) ? (st + 2) : 7;
#pragma unroll
    for (int ss = 0; ss < 2; ++ss)
      pr[ss] = __builtin_nontemporal_load((const f32x4*)(prp + tf * 32 + 16 * ss));
    // scores out
#pragma unroll
    for (int ss = 0; ss < 2; ++ss)
      __builtin_nontemporal_store(acc[ss], (f32x4*)(scp + s0 + 16 * ss));

    if (st <= pvmax) {  // tiles fully in the causal-masked region skip softmax/PV
      float tm = fmaxf(fmaxf(fmaxf(acc[0][0], acc[0][1]), fmaxf(acc[0][2], acc[0][3])),
                       fmaxf(fmaxf(acc[1][0], acc[1][1]), fmaxf(acc[1][2], acc[1][3])));
      tm = fmaxf(tm, __shfl_xor(tm, 16));
      tm = fmaxf(tm, __shfl_xor(tm, 32));
      tm *= temp;
      const float mnew = fmaxf(m, tm);
      const float fct = __expf(m - mnew);
      m = mnew;
      float p[8];
#pragma unroll
      for (int ss = 0; ss < 2; ++ss)
#pragma unroll
        for (int r = 0; r < 4; ++r)
          p[ss * 4 + r] = __expf(fmaf(temp, acc[ss][r], -mnew));
      float ts = (p[0] + p[1]) + (p[2] + p[3]) + (p[4] + p[5]) + (p[6] + p[7]);
      ts += __shfl_xor(ts, 16);
      ts += __shfl_xor(ts, 32);
      lsum = lsum * fct + ts;
#pragma unroll
      for (int ds = 0; ds < 4; ++ds) O[ds] *= fct;

      // pack P to bf16 and redistribute in-register to the PV B-fragment
      // layout (lane (ql,g) needs s = s0+8g..8g+7). Held: w0 = s 4g..4g+3,
      // w1 = s 16+4g..+3. Sources: lanes g'={2g&3, (2g+1)&3}, pick w0/w1 by g<2.
      const int w0x = (int)pk(p[0], p[1]), w0y = (int)pk(p[2], p[3]);
      const int w1x = (int)pk(p[4], p[5]), w1y = (int)pk(p[6], p[7]);
      const int srcA = ((g & 1) << 5) + ql;       // lane of g' = (2g)&3
      const int a0 = __shfl(w0x, srcA),      a1 = __shfl(w1x, srcA);
      const int b0 = __shfl(w0y, srcA),      b1 = __shfl(w1y, srcA);
      const int c0 = __shfl(w0x, srcA + 16), c1 = __shfl(w1x, srcA + 16);
      const int d0 = __shfl(w0y, srcA + 16), d1 = __shfl(w1y, srcA + 16);
      union { i32x4 i; bfrag b; } pu;
      pu.i = i32x4{g < 2 ? a0 : a1, g < 2 ? b0 : b1,
                   g < 2 ? c0 : c1, g < 2 ? d0 : d1};

      // PV swapped: O^T[d][q] += V^T[d x s32] * P^T[s32 x q16]
      bfrag vf[4];
#pragma unroll
      for (int ds = 0; ds < 4; ++ds)
        vf[ds] = *(const bfrag*)(&Vt[(16 * ds + ql) * 266 + s0 + g * 8]);
#pragma unroll
      for (int ds = 0; ds < 4; ++ds) O[ds] = MFMA(vf[ds], pu.b, O[ds]);
    }
  };

#pragma unroll 1
  for (int st = 0; st < 8; st += 2) {
    tile_body(st, prA);
    tile_body(st + 1, prB);
  }

  // epilogue: O /= l, store dwordx4 (d-consecutive regs)
  {
    const float inv = 1.f / lsum;
    float* op = Ov + (size_t)bn * 131072 + (size_t)q * 512 + h * 64 + 4 * g;
#pragma unroll
    for (int ds = 0; ds < 4; ++ds) {
      f32x4 o = O[ds] * inv;
      *(f32x4*)(op + 16 * ds) = o;
    }
  }
}

extern "C" void kernel_launch(void* const* d_in, const int* in_sizes, int n_in,
                              void* d_out, int out_size, void* d_ws, size_t ws_size,
                              hipStream_t stream) {
  const float* Qg = (const float*)d_in[0];   // queries  [B,N,L,H,E]
  const float* Kg = (const float*)d_in[1];   // keys     [B,N,S,H,E]
  const float* Vg = (const float*)d_in[2];   // values   [B,N,S,H,D]
  const float* Pg = (const float*)d_in[4];   // attn_scores [B,N,H,L,S]
  float* Sc = (float*)d_out;                            // scores out
  float* Ov = Sc + (size_t)4 * 32 * 8 * 256 * 256;      // V out
  attn_kernel<<<dim3(1024), dim3(1024), 0, stream>>>(Qg, Kg, Vg, Pg, Sc, Ov);
}

// Round 5
// 265.146 us; speedup vs baseline: 1.3352x; 1.3352x over previous
//
#include <hip/hip_runtime.h>
#include <stdint.h>

// B=4 N=32 L=S=256 H=8 E=D=64
// grid = B*N*H = 1024 blocks, 1024 threads (16 waves), one (b,n,h) per block.
// Each wave owns 16 q-rows. Swapped-operand MFMA: QK tile D[s][q] (col=q=lane&15),
// PV tile D[d][q]. LDS 70.9KB -> 2 blocks/CU; VGPR capped 64 -> 32 waves/CU.
// R4: depth-2 prior prefetch via MACRO double-buffer (named vars, literal
// indices only -- no pointer aliasing, arrays stay in VGPRs; R3 lesson).

typedef __attribute__((ext_vector_type(8))) short bfrag;   // 8 bf16 (4 VGPRs)
typedef __attribute__((ext_vector_type(4))) float f32x4;
typedef __attribute__((ext_vector_type(4))) int i32x4;

__device__ __forceinline__ uint32_t f2bf(float f) {
  uint32_t u = __builtin_bit_cast(uint32_t, f);
  return (u + 0x7FFFu + ((u >> 16) & 1u)) >> 16;   // RNE f32->bf16 (finite data)
}
__device__ __forceinline__ uint32_t pk(float a, float b) {
  return f2bf(a) | (f2bf(b) << 16);
}

#define MFMA(a, b, c) __builtin_amdgcn_mfma_f32_16x16x32_bf16((a), (b), (c), 0, 0, 0)

__global__ __launch_bounds__(1024, 8) void attn_kernel(
    const float* __restrict__ Qg, const float* __restrict__ Kg,
    const float* __restrict__ Vg, const float* __restrict__ Pg,
    float* __restrict__ Sc, float* __restrict__ Ov)
{
  // K rows padded to 72 shorts (2-way bank alias = free); Vt rows 266 shorts.
  __shared__ unsigned short Ks[256 * 72];   // 36864 B
  __shared__ unsigned short Vt[64 * 266];   // 34048 B  (total 70912 B)

  const int bnh = blockIdx.x;
  const int bn = bnh >> 3, h = bnh & 7;
  const int t = threadIdx.x;

  // ---- stage K as bf16 [s][e] : 64 rows/iter x 4 iters ----
  {
    const int e0 = (t & 15) * 4;
    const int rb = t >> 4;                       // 0..63
    const float* kp = Kg + (size_t)bn * 131072 + h * 64 + e0;
#pragma unroll
    for (int it = 0; it < 4; ++it) {
      const int r = it * 64 + rb;
      const f32x4 k4 = *(const f32x4*)(kp + (size_t)r * 512);
      uint2 kk;
      kk.x = pk(k4.x, k4.y);
      kk.y = pk(k4.z, k4.w);
      *(uint2*)(&Ks[r * 72 + e0]) = kk;
    }
  }
  // ---- stage V transposed as bf16 [d][s] : 16 s-groups x 4 iters ----
  {
    const int d = t & 63, sg = t >> 6;           // sg 0..15
    const float* vp = Vg + (size_t)bn * 131072 + h * 64 + d;
#pragma unroll
    for (int it = 0; it < 4; ++it) {
      const int sv = it * 64 + sg * 4;
      const float v0 = vp[(size_t)(sv + 0) * 512];
      const float v1 = vp[(size_t)(sv + 1) * 512];
      const float v2 = vp[(size_t)(sv + 2) * 512];
      const float v3 = vp[(size_t)(sv + 3) * 512];
      uint2 vv;
      vv.x = pk(v0, v1);
      vv.y = pk(v2, v3);
      *(uint2*)(&Vt[d * 266 + sv]) = vv;
    }
  }

  const int lane = t & 63;
  const int wave = t >> 6;    // 0..15
  const int ql = lane & 15;   // q within 16-tile (MFMA col)
  const int g  = lane >> 4;   // 4-group (MFMA row group / k-slice)
  const int qbase = wave * 16;
  const int q = qbase + ql;
  const float temp = 0.125f;  // 1/sqrt(64)

  // ---- Q fragments direct from global (B-operand of swapped QK) ----
  bfrag qf[2];
#pragma unroll
  for (int ks = 0; ks < 2; ++ks) {
    const float* qp = Qg + (size_t)bn * 131072 + (size_t)q * 512 + h * 64 + ks * 32 + g * 8;
    const f32x4 qa = *(const f32x4*)qp;
    const f32x4 qb = *(const f32x4*)(qp + 4);
    union { i32x4 i; bfrag b; } u;
    u.i = i32x4{(int)pk(qa.x, qa.y), (int)pk(qa.z, qa.w),
                (int)pk(qb.x, qb.y), (int)pk(qb.z, qb.w)};
    qf[ks] = u.b;
  }

  __syncthreads();

  f32x4 O[4];
#pragma unroll
  for (int ds = 0; ds < 4; ++ds) O[ds] = f32x4{0.f, 0.f, 0.f, 0.f};
  float m = -1e30f, lsum = 0.f;

  const size_t scb = (size_t)bnh << 16;
  const float* prp = Pg + scb + (size_t)q * 256 + 4 * g;   // + 16*ss + 32*st
  float* scp = Sc + scb + (size_t)q * 256 + 4 * g;
  const int pvmax = wave >> 1;   // causal: PV only for st <= pvmax

  // depth-2 prior pipeline, NAMED buffers (literal indices only)
  f32x4 prA[2], prB[2];
  prA[0] = __builtin_nontemporal_load((const f32x4*)(prp));
  prA[1] = __builtin_nontemporal_load((const f32x4*)(prp + 16));
  prB[0] = __builtin_nontemporal_load((const f32x4*)(prp + 32));
  prB[1] = __builtin_nontemporal_load((const f32x4*)(prp + 48));

#define TILE_BODY(ST, PR)                                                      \
  {                                                                            \
    const int s0 = (ST) * 32;                                                  \
    bfrag kf[2][2];                                                            \
    _Pragma("unroll") for (int ss = 0; ss < 2; ++ss)                           \
        _Pragma("unroll") for (int ks = 0; ks < 2; ++ks)                       \
            kf[ss][ks] =                                                       \
        *(const bfrag*)(&Ks[(s0 + 16 * ss + ql) * 72 + ks * 32 + g * 8]);      \
    f32x4 acc[2];                                                              \
    _Pragma("unroll") for (int ss = 0; ss < 2; ++ss) {                         \
      f32x4 a = f32x4{0.f, 0.f, 0.f, 0.f};                                     \
      a = MFMA(kf[ss][0], qf[0], a);                                           \
      a = MFMA(kf[ss][1], qf[1], a);                                           \
      const int sb = s0 + 16 * ss + 4 * g;                                     \
      _Pragma("unroll") for (int r = 0; r < 4; ++r)                            \
          a[r] = (sb + r <= q) ? a[r] : a[r] - 1e9f;                           \
      acc[ss] = a + PR[ss];                                                    \
    }                                                                          \
    /* prefetch prior for tile ST+2 into the buffer just consumed */           \
    {                                                                          \
      const int tf = ((ST) + 2 < 8) ? (ST) + 2 : 7;                            \
      PR[0] = __builtin_nontemporal_load((const f32x4*)(prp + tf * 32));       \
      PR[1] = __builtin_nontemporal_load((const f32x4*)(prp + tf * 32 + 16));  \
    }                                                                          \
    _Pragma("unroll") for (int ss = 0; ss < 2; ++ss)                           \
        __builtin_nontemporal_store(acc[ss], (f32x4*)(scp + s0 + 16 * ss));    \
    if ((ST) <= pvmax) {                                                       \
      float tm =                                                               \
          fmaxf(fmaxf(fmaxf(acc[0][0], acc[0][1]), fmaxf(acc[0][2], acc[0][3])), \
                fmaxf(fmaxf(acc[1][0], acc[1][1]), fmaxf(acc[1][2], acc[1][3]))); \
      tm = fmaxf(tm, __shfl_xor(tm, 16));                                      \
      tm = fmaxf(tm, __shfl_xor(tm, 32));                                      \
      tm *= temp;                                                              \
      const float mnew = fmaxf(m, tm);                                         \
      const float fct = __expf(m - mnew);                                      \
      m = mnew;                                                                \
      float p[8];                                                              \
      _Pragma("unroll") for (int ss = 0; ss < 2; ++ss)                         \
          _Pragma("unroll") for (int r = 0; r < 4; ++r)                        \
              p[ss * 4 + r] = __expf(fmaf(temp, acc[ss][r], -mnew));           \
      float ts = (p[0] + p[1]) + (p[2] + p[3]) + (p[4] + p[5]) + (p[6] + p[7]); \
      ts += __shfl_xor(ts, 16);                                                \
      ts += __shfl_xor(ts, 32);                                                \
      lsum = lsum * fct + ts;                                                  \
      _Pragma("unroll") for (int ds = 0; ds < 4; ++ds) O[ds] *= fct;           \
      const int w0x = (int)pk(p[0], p[1]), w0y = (int)pk(p[2], p[3]);          \
      const int w1x = (int)pk(p[4], p[5]), w1y = (int)pk(p[6], p[7]);          \
      const int srcA = ((g & 1) << 5) + ql;                                    \
      const int a0 = __shfl(w0x, srcA), a1 = __shfl(w1x, srcA);                \
      const int b0 = __shfl(w0y, srcA), b1 = __shfl(w1y, srcA);                \
      const int c0 = __shfl(w0x, srcA + 16), c1 = __shfl(w1x, srcA + 16);      \
      const int d0 = __shfl(w0y, srcA + 16), d1 = __shfl(w1y, srcA + 16);      \
      union { i32x4 i; bfrag b; } pu;                                          \
      pu.i = i32x4{g < 2 ? a0 : a1, g < 2 ? b0 : b1, g < 2 ? c0 : c1,          \
                   g < 2 ? d0 : d1};                                           \
      bfrag vf[4];                                                             \
      _Pragma("unroll") for (int ds = 0; ds < 4; ++ds)                         \
          vf[ds] = *(const bfrag*)(&Vt[(16 * ds + ql) * 266 + s0 + g * 8]);    \
      _Pragma("unroll") for (int ds = 0; ds < 4; ++ds)                         \
          O[ds] = MFMA(vf[ds], pu.b, O[ds]);                                   \
    }                                                                          \
  }

  TILE_BODY(0, prA)
  TILE_BODY(1, prB)
  TILE_BODY(2, prA)
  TILE_BODY(3, prB)
  TILE_BODY(4, prA)
  TILE_BODY(5, prB)
  TILE_BODY(6, prA)
  TILE_BODY(7, prB)
#undef TILE_BODY

  // epilogue: O /= l, store dwordx4 (d-consecutive regs)
  {
    const float inv = 1.f / lsum;
    float* op = Ov + (size_t)bn * 131072 + (size_t)q * 512 + h * 64 + 4 * g;
#pragma unroll
    for (int ds = 0; ds < 4; ++ds) {
      f32x4 o = O[ds] * inv;
      *(f32x4*)(op + 16 * ds) = o;
    }
  }
}

extern "C" void kernel_launch(void* const* d_in, const int* in_sizes, int n_in,
                              void* d_out, int out_size, void* d_ws, size_t ws_size,
                              hipStream_t stream) {
  const float* Qg = (const float*)d_in[0];   // queries  [B,N,L,H,E]
  const float* Kg = (const float*)d_in[1];   // keys     [B,N,S,H,E]
  const float* Vg = (const float*)d_in[2];   // values   [B,N,S,H,D]
  const float* Pg = (const float*)d_in[4];   // attn_scores [B,N,H,L,S]
  float* Sc = (float*)d_out;                            // scores out
  float* Ov = Sc + (size_t)4 * 32 * 8 * 256 * 256;      // V out
  attn_kernel<<<dim3(1024), dim3(1024), 0, stream>>>(Qg, Kg, Vg, Pg, Sc, Ov);
}

// Round 6
// 155.223 us; speedup vs baseline: 2.2807x; 1.7082x over previous
//
#include <hip/hip_runtime.h>
#include <stdint.h>

// B=4 N=32 L=S=256 H=8 E=D=64
// grid = B*N*H = 1024 blocks, 1024 threads (16 waves), one (b,n,h) per block.
// Each wave owns 16 q-rows. Swapped-operand MFMA: QK tile D[s][q] (col=q=lane&15),
// PV tile D[d][q]. LDS 70.9KB -> 2 blocks/CU.
// R5: R2 structure (rolled loop, natural VGPR alloc) + zero-cost prior
// prefetch: issue tile st+1's prior loads right after tile st's prior is
// consumed (before stores+softmax+PV), as loop-carried SCALARS pr0/pr1.

typedef __attribute__((ext_vector_type(8))) short bfrag;   // 8 bf16 (4 VGPRs)
typedef __attribute__((ext_vector_type(4))) float f32x4;
typedef __attribute__((ext_vector_type(4))) int i32x4;

__device__ __forceinline__ uint32_t f2bf(float f) {
  uint32_t u = __builtin_bit_cast(uint32_t, f);
  return (u + 0x7FFFu + ((u >> 16) & 1u)) >> 16;   // RNE f32->bf16 (finite data)
}
__device__ __forceinline__ uint32_t pk(float a, float b) {
  return f2bf(a) | (f2bf(b) << 16);
}

#define MFMA(a, b, c) __builtin_amdgcn_mfma_f32_16x16x32_bf16((a), (b), (c), 0, 0, 0)

__global__ __launch_bounds__(1024, 2) void attn_kernel(
    const float* __restrict__ Qg, const float* __restrict__ Kg,
    const float* __restrict__ Vg, const float* __restrict__ Pg,
    float* __restrict__ Sc, float* __restrict__ Ov)
{
  // K rows padded to 72 shorts (2-way bank alias on b128 = minimum possible);
  // Vt rows 266 shorts (533 banks % 32 = 5, coprime -> conflict-free reads).
  __shared__ unsigned short Ks[256 * 72];   // 36864 B
  __shared__ unsigned short Vt[64 * 266];   // 34048 B  (total 70912 B)

  const int bnh = blockIdx.x;
  const int bn = bnh >> 3, h = bnh & 7;
  const int t = threadIdx.x;

  // ---- stage K as bf16 [s][e] : 64 rows/iter x 4 iters ----
  {
    const int e0 = (t & 15) * 4;
    const int rb = t >> 4;                       // 0..63
    const float* kp = Kg + (size_t)bn * 131072 + h * 64 + e0;
#pragma unroll
    for (int it = 0; it < 4; ++it) {
      const int r = it * 64 + rb;
      const f32x4 k4 = *(const f32x4*)(kp + (size_t)r * 512);
      uint2 kk;
      kk.x = pk(k4.x, k4.y);
      kk.y = pk(k4.z, k4.w);
      *(uint2*)(&Ks[r * 72 + e0]) = kk;
    }
  }
  // ---- stage V transposed as bf16 [d][s] : 16 s-groups x 4 iters ----
  {
    const int d = t & 63, sg = t >> 6;           // sg 0..15
    const float* vp = Vg + (size_t)bn * 131072 + h * 64 + d;
#pragma unroll
    for (int it = 0; it < 4; ++it) {
      const int sv = it * 64 + sg * 4;
      const float v0 = vp[(size_t)(sv + 0) * 512];
      const float v1 = vp[(size_t)(sv + 1) * 512];
      const float v2 = vp[(size_t)(sv + 2) * 512];
      const float v3 = vp[(size_t)(sv + 3) * 512];
      uint2 vv;
      vv.x = pk(v0, v1);
      vv.y = pk(v2, v3);
      *(uint2*)(&Vt[d * 266 + sv]) = vv;
    }
  }

  const int lane = t & 63;
  const int wave = t >> 6;    // 0..15
  const int ql = lane & 15;   // q within 16-tile (MFMA col)
  const int g  = lane >> 4;   // 4-group (MFMA row group / k-slice)
  const int qbase = wave * 16;
  const int q = qbase + ql;
  const float temp = 0.125f;  // 1/sqrt(64)

  // ---- Q fragments direct from global (B-operand of swapped QK) ----
  bfrag qf[2];
#pragma unroll
  for (int ks = 0; ks < 2; ++ks) {
    const float* qp = Qg + (size_t)bn * 131072 + (size_t)q * 512 + h * 64 + ks * 32 + g * 8;
    const f32x4 qa = *(const f32x4*)qp;
    const f32x4 qb = *(const f32x4*)(qp + 4);
    union { i32x4 i; bfrag b; } u;
    u.i = i32x4{(int)pk(qa.x, qa.y), (int)pk(qa.z, qa.w),
                (int)pk(qb.x, qb.y), (int)pk(qb.z, qb.w)};
    qf[ks] = u.b;
  }

  __syncthreads();

  f32x4 O[4];
#pragma unroll
  for (int ds = 0; ds < 4; ++ds) O[ds] = f32x4{0.f, 0.f, 0.f, 0.f};
  float m = -1e30f, lsum = 0.f;

  const size_t scb = (size_t)bnh << 16;
  const float* prp = Pg + scb + (size_t)q * 256 + 4 * g;   // + 16*ss + 32*st
  float* scp = Sc + scb + (size_t)q * 256 + 4 * g;
  const int pvmax = wave >> 1;   // causal: PV only for st <= pvmax

  // prior pipeline: loop-carried scalars, loaded for tile 0 here
  f32x4 pr0 = __builtin_nontemporal_load((const f32x4*)(prp));
  f32x4 pr1 = __builtin_nontemporal_load((const f32x4*)(prp + 16));

#pragma unroll 1
  for (int st = 0; st < 8; ++st) {
    const int s0 = st * 32;
    bfrag kf[2][2];
#pragma unroll
    for (int ss = 0; ss < 2; ++ss)
#pragma unroll
      for (int ks = 0; ks < 2; ++ks)
        kf[ss][ks] = *(const bfrag*)(&Ks[(s0 + 16 * ss + ql) * 72 + ks * 32 + g * 8]);

    // QK^T swapped -> D[s16][q16]; regs are s-consecutive at fixed q
    f32x4 acc[2];
#pragma unroll
    for (int ss = 0; ss < 2; ++ss) {
      f32x4 a = f32x4{0.f, 0.f, 0.f, 0.f};
      a = MFMA(kf[ss][0], qf[0], a);
      a = MFMA(kf[ss][1], qf[1], a);
      const int sb = s0 + 16 * ss + 4 * g;
      // analytic causal mask: s<=q allowed, else -1e9 (matches input mask)
#pragma unroll
      for (int r = 0; r < 4; ++r)
        a[r] = (sb + r <= q) ? a[r] : a[r] - 1e9f;
      acc[ss] = a + (ss == 0 ? pr0 : pr1);   // scores = QK + mask + prior
    }

    // prior consumed -> issue next tile's loads NOW (hidden under the
    // stores + softmax + PV below; zero extra registers, same two carried)
    if (st < 7) {
      pr0 = __builtin_nontemporal_load((const f32x4*)(prp + (st + 1) * 32));
      pr1 = __builtin_nontemporal_load((const f32x4*)(prp + (st + 1) * 32 + 16));
    }

    // scores out
    __builtin_nontemporal_store(acc[0], (f32x4*)(scp + s0));
    __builtin_nontemporal_store(acc[1], (f32x4*)(scp + s0 + 16));

    if (st <= pvmax) {  // tiles fully in the causal-masked region skip softmax/PV
      float tm = fmaxf(fmaxf(fmaxf(acc[0][0], acc[0][1]), fmaxf(acc[0][2], acc[0][3])),
                       fmaxf(fmaxf(acc[1][0], acc[1][1]), fmaxf(acc[1][2], acc[1][3])));
      tm = fmaxf(tm, __shfl_xor(tm, 16));
      tm = fmaxf(tm, __shfl_xor(tm, 32));
      tm *= temp;
      const float mnew = fmaxf(m, tm);
      const float fct = __expf(m - mnew);
      m = mnew;
      float p[8];
#pragma unroll
      for (int ss = 0; ss < 2; ++ss)
#pragma unroll
        for (int r = 0; r < 4; ++r)
          p[ss * 4 + r] = __expf(fmaf(temp, acc[ss][r], -mnew));
      float ts = (p[0] + p[1]) + (p[2] + p[3]) + (p[4] + p[5]) + (p[6] + p[7]);
      ts += __shfl_xor(ts, 16);
      ts += __shfl_xor(ts, 32);
      lsum = lsum * fct + ts;
#pragma unroll
      for (int ds = 0; ds < 4; ++ds) O[ds] *= fct;

      // pack P to bf16 and redistribute in-register to the PV B-fragment
      // layout (lane (ql,g) needs s = s0+8g..8g+7). Held: w0 = s 4g..4g+3,
      // w1 = s 16+4g..+3. Sources: lanes g'={2g&3, (2g+1)&3}, pick w0/w1 by g<2.
      const int w0x = (int)pk(p[0], p[1]), w0y = (int)pk(p[2], p[3]);
      const int w1x = (int)pk(p[4], p[5]), w1y = (int)pk(p[6], p[7]);
      const int srcA = ((g & 1) << 5) + ql;       // lane of g' = (2g)&3
      const int a0 = __shfl(w0x, srcA),      a1 = __shfl(w1x, srcA);
      const int b0 = __shfl(w0y, srcA),      b1 = __shfl(w1y, srcA);
      const int c0 = __shfl(w0x, srcA + 16), c1 = __shfl(w1x, srcA + 16);
      const int d0 = __shfl(w0y, srcA + 16), d1 = __shfl(w1y, srcA + 16);
      union { i32x4 i; bfrag b; } pu;
      pu.i = i32x4{g < 2 ? a0 : a1, g < 2 ? b0 : b1,
                   g < 2 ? c0 : c1, g < 2 ? d0 : d1};

      // PV swapped: O^T[d][q] += V^T[d x s32] * P^T[s32 x q16]
      bfrag vf[4];
#pragma unroll
      for (int ds = 0; ds < 4; ++ds)
        vf[ds] = *(const bfrag*)(&Vt[(16 * ds + ql) * 266 + s0 + g * 8]);
#pragma unroll
      for (int ds = 0; ds < 4; ++ds) O[ds] = MFMA(vf[ds], pu.b, O[ds]);
    }
  }

  // epilogue: O /= l, store dwordx4 (d-consecutive regs)
  {
    const float inv = 1.f / lsum;
    float* op = Ov + (size_t)bn * 131072 + (size_t)q * 512 + h * 64 + 4 * g;
#pragma unroll
    for (int ds = 0; ds < 4; ++ds) {
      f32x4 o = O[ds] * inv;
      *(f32x4*)(op + 16 * ds) = o;
    }
  }
}

extern "C" void kernel_launch(void* const* d_in, const int* in_sizes, int n_in,
                              void* d_out, int out_size, void* d_ws, size_t ws_size,
                              hipStream_t stream) {
  const float* Qg = (const float*)d_in[0];   // queries  [B,N,L,H,E]
  const float* Kg = (const float*)d_in[1];   // keys     [B,N,S,H,E]
  const float* Vg = (const float*)d_in[2];   // values   [B,N,S,H,D]
  const float* Pg = (const float*)d_in[4];   // attn_scores [B,N,H,L,S]
  float* Sc = (float*)d_out;                            // scores out
  float* Ov = Sc + (size_t)4 * 32 * 8 * 256 * 256;      // V out
  attn_kernel<<<dim3(1024), dim3(1024), 0, stream>>>(Qg, Kg, Vg, Pg, Sc, Ov);
}